// Round 18
// baseline (195.639 us; speedup 1.0000x reference)
//
#include <hip/hip_runtime.h>

#define NQ 16384
#define NV 16384
#define DMODEL 256
#define SAMPN (4 * 16384 * 8)   // one plane: B*NQ*HEADS float4s
#define VPLANE 65536            // value plane: B*NV pixels (head-major layout)

typedef __bf16 bf16x8 __attribute__((ext_vector_type(8)));
typedef float f32x4 __attribute__((ext_vector_type(4)));

__device__ __forceinline__ unsigned short f2bf(float x) {
    union { float f; unsigned int u; } v; v.f = x;
    unsigned int r = v.u + 0x7fff + ((v.u >> 16) & 1);
    return (unsigned short)(r >> 16);
}
__device__ __forceinline__ float blo(unsigned int u) {
    union { unsigned int u; float f; } v; v.u = u << 16; return v.f;
}
__device__ __forceinline__ float bhi(unsigned int u) {
    union { unsigned int u; float f; } v; v.u = u & 0xFFFF0000u; return v.f;
}
__device__ __forceinline__ f32x4 mfma16(bf16x8 a, bf16x8 b, f32x4 c) {
    return __builtin_amdgcn_mfma_f32_16x16x32_bf16(a, b, c, 0, 0, 0);
}

// ---------------- prep: scaled transposed weights + LN-fold constants ----------------
__global__ __launch_bounds__(256) void k_prep(
    const float* __restrict__ Wv, const float* __restrict__ Woff,
    const float* __restrict__ Wattn, const float* __restrict__ Wout,
    const float* __restrict__ fns, const float* __restrict__ fnb,
    const float* __restrict__ qns, const float* __restrict__ qnb,
    const float* __restrict__ b_value, const float* __restrict__ b_off,
    const float* __restrict__ b_attn,
    unsigned short* __restrict__ WtV, unsigned short* __restrict__ WtC,
    unsigned short* __restrict__ WtO,
    float* __restrict__ csumV, float* __restrict__ preV,
    float* __restrict__ csumC, float* __restrict__ preC) {
    const int blk = blockIdx.x;
    if (blk < 608) {
        int t = blk * 256 + threadIdx.x;
        if (t < 65536) { int n = t >> 8, k = t & 255; WtV[t] = f2bf(fns[k] * Wv[k * 256 + n]); return; }
        t -= 65536;
        if (t < 65536) { int n = t >> 8, k = t & 255; WtO[t] = f2bf(Wout[k * 256 + n]); return; }
        t -= 65536;
        if (t < 24576) {
            int j = t >> 8, k = t & 255;
            float w = (j < 64) ? Woff[k * 64 + j] : Wattn[k * 32 + (j - 64)];
            WtC[j * 256 + k] = f2bf(qns[k] * w);
        }
        return;
    }
    if (blk < 612) {   // csumV / preV
        __shared__ float sCS[4][64], sPR[4][64];
        const int nl = threadIdx.x & 63;
        const int n = (blk - 608) * 64 + nl;
        const int kp = threadIdx.x >> 6;
        float cs = 0.f, pr = 0.f;
        for (int k = kp * 64; k < kp * 64 + 64; ++k) {
            float w = Wv[k * 256 + n];
            cs += fns[k] * w;
            pr += fnb[k] * w;
        }
        sCS[kp][nl] = cs; sPR[kp][nl] = pr;
        __syncthreads();
        if (threadIdx.x < 64) {
            int nn = (blk - 608) * 64 + threadIdx.x;
            csumV[nn] = sCS[0][threadIdx.x] + sCS[1][threadIdx.x] + sCS[2][threadIdx.x] + sCS[3][threadIdx.x];
            preV[nn] = sPR[0][threadIdx.x] + sPR[1][threadIdx.x] + sPR[2][threadIdx.x] + sPR[3][threadIdx.x]
                       + b_value[nn];
        }
        return;
    }
    {   // blk == 612: csumC / preC
        __shared__ float sCS[2][96], sPR[2][96];
        const int t = threadIdx.x;
        if (t < 192) {
            const int n = t % 96;
            const int kp = t / 96;
            float cs = 0.f, pr = 0.f;
            for (int k = kp * 128; k < kp * 128 + 128; ++k) {
                float w = (n < 64) ? Woff[k * 64 + n] : Wattn[k * 32 + (n - 64)];
                cs += qns[k] * w;
                pr += qnb[k] * w;
            }
            sCS[kp][n] = cs; sPR[kp][n] = pr;
        }
        __syncthreads();
        if (t < 96) {
            csumC[t] = sCS[0][t] + sCS[1][t];
            preC[t] = sPR[0][t] + sPR[1][t] + ((t < 64) ? b_off[t] : b_attn[t - 64]);
        }
        return;
    }
}

// ---------------- spatial binning of queries by ref tile (8x8 px, 256 tiles/batch) ----------------
__global__ __launch_bounds__(256) void k_hist(
    const float* __restrict__ refpt, int* __restrict__ hist) {
    const int q = blockIdx.x * 256 + threadIdx.x;
    const int b = q >> 14;
    float rx = refpt[(size_t)q * 2 + 0], ry = refpt[(size_t)q * 2 + 1];
    int px = min(max((int)(rx * 128.f), 0), 127);
    int py = min(max((int)(ry * 128.f), 0), 127);
    int bucket = (b << 8) | ((py >> 3) << 4) | (px >> 3);
    atomicAdd(&hist[bucket], 1);
}

__global__ __launch_bounds__(256) void k_scan(
    const int* __restrict__ hist, int* __restrict__ base, int* __restrict__ cursor) {
    __shared__ int tmp[256];
    const int t = threadIdx.x;
    int4 h4 = ((const int4*)hist)[t];
    int tsum = h4.x + h4.y + h4.z + h4.w;
    tmp[t] = tsum;
    __syncthreads();
    for (int d = 1; d < 256; d <<= 1) {
        int v = (t >= d) ? tmp[t - d] : 0;
        __syncthreads();
        tmp[t] += v;
        __syncthreads();
    }
    int excl = tmp[t] - tsum;
    int4 b4;
    b4.x = excl; b4.y = excl + h4.x; b4.z = b4.y + h4.y; b4.w = b4.z + h4.z;
    ((int4*)base)[t] = b4;
    ((int4*)cursor)[t] = b4;
}

__global__ __launch_bounds__(256) void k_perm(
    const float* __restrict__ refpt, int* __restrict__ cursor, int* __restrict__ perm) {
    const int q = blockIdx.x * 256 + threadIdx.x;
    const int b = q >> 14;
    float rx = refpt[(size_t)q * 2 + 0], ry = refpt[(size_t)q * 2 + 1];
    int px = min(max((int)(rx * 128.f), 0), 127);
    int py = min(max((int)(ry * 128.f), 0), 127);
    int bucket = (b << 8) | ((py >> 3) << 4) | (px >> 3);
    int slot = atomicAdd(&cursor[bucket], 1);
    perm[slot] = q;
}

// Coalesced fp32->bf16 stage (64 rows) + LDS-based row stats (4 threads/row).
#define STAGE_LNSTATS64(srcptr)                                                       \
    {                                                                                 \
        const int t = threadIdx.x;                                                    \
        const float4* src4 = (const float4*)((srcptr) + (size_t)m0 * 256);            \
        _Pragma("unroll 8") for (int i = 0; i < 16; ++i) {                            \
            float4 x = src4[i * 256 + t];                                             \
            const int row = i * 4 + (t >> 6);                                         \
            uint2 pk;                                                                 \
            pk.x = (unsigned)f2bf(x.x) | ((unsigned)f2bf(x.y) << 16);                 \
            pk.y = (unsigned)f2bf(x.z) | ((unsigned)f2bf(x.w) << 16);                 \
            *(uint2*)&A[row * 264 + (t & 63) * 4] = pk;                               \
        }                                                                             \
    }                                                                                 \
    __syncthreads();                                                                  \
    {                                                                                 \
        const int t = threadIdx.x;                                                    \
        const int r = t >> 2, h = t & 3;                                              \
        float s = 0.f, sq = 0.f;                                                      \
        _Pragma("unroll") for (int j = 0; j < 8; ++j) {                               \
            uint4 u = *(const uint4*)&A[r * 264 + h * 64 + j * 8];                    \
            float v0 = blo(u.x), v1 = bhi(u.x), v2 = blo(u.y), v3 = bhi(u.y);         \
            float v4 = blo(u.z), v5 = bhi(u.z), v6 = blo(u.w), v7 = bhi(u.w);         \
            s += v0 + v1 + v2 + v3 + v4 + v5 + v6 + v7;                               \
            sq += v0 * v0 + v1 * v1 + v2 * v2 + v3 * v3 +                             \
                  v4 * v4 + v5 * v5 + v6 * v6 + v7 * v7;                              \
        }                                                                             \
        s += __shfl_xor(s, 1);  sq += __shfl_xor(sq, 1);                              \
        s += __shfl_xor(s, 2);  sq += __shfl_xor(sq, 2);                              \
        if (h == 0) {                                                                 \
            float mu = s * 0.00390625f;                                               \
            muL[r] = mu;                                                              \
            rsL[r] = rsqrtf(sq * 0.00390625f - mu * mu + 1e-6f);                      \
        }                                                                             \
    }

#define STAGE_A64(srcbuf)                                                             \
    {                                                                                 \
        const int c = threadIdx.x & 31;                                               \
        const int rt = threadIdx.x >> 5;                                              \
        _Pragma("unroll") for (int i = 0; i < 8; ++i) {                               \
            const int r = rt + i * 8;                                                 \
            *(uint4*)&A[r * 264 + c * 8] =                                            \
                *(const uint4*)((srcbuf) + (size_t)(m0 + r) * 256 + c * 8);           \
        }                                                                             \
    }

#define MFMA_STEP4(bf, kk)                                                            \
    _Pragma("unroll") for (int m = 0; m < 4; ++m) {                                   \
        bf16x8 a = *(const bf16x8*)&A[(m * 16 + lrow) * 264 + (kk) * 32 + lk];        \
        _Pragma("unroll") for (int i = 0; i < 4; ++i)                                 \
            acc[i][m] = mfma16(bf[i], a, acc[i][m]);                                  \
    }

// ---------------- fused MLP dispatch: even blocks = value-tile, odd = qoff-tile ----------------
__global__ __launch_bounds__(256, 4) void k_mlp(
    const float* __restrict__ feat, const float* __restrict__ csumV,
    const float* __restrict__ preV, const unsigned short* __restrict__ WtV,
    unsigned short* __restrict__ value,
    const float* __restrict__ query, const float* __restrict__ refpt,
    const float* __restrict__ csumC, const float* __restrict__ preC,
    const unsigned short* __restrict__ WtC, float4* __restrict__ samples) {
    __shared__ unsigned short A[64 * 264];
    __shared__ float muL[64], rsL[64];
    const int blk = blockIdx.x;
    const int m0 = (blk >> 1) * 64;
    const int lane = threadIdx.x & 63;
    const int w = threadIdx.x >> 6;

    if ((blk & 1) == 0) {
        // ---- value path (LDS-staged GEMM, LN folded into epilogue) ----
        STAGE_LNSTATS64(feat)
        const int lrow = lane & 15, lk = (lane >> 4) * 8;
        f32x4 acc[4][4];
#pragma unroll
        for (int i = 0; i < 4; ++i)
#pragma unroll
            for (int m = 0; m < 4; ++m) acc[i][m] = (f32x4){0.f, 0.f, 0.f, 0.f};
#define LOADB_V(dst, kk)                                                              \
    _Pragma("unroll") for (int i = 0; i < 4; ++i) dst[i] =                            \
        *(const bf16x8*)(WtV + (size_t)((w * 4 + i) * 16 + lrow) * 256 + (kk) * 32 + lk);
        {
            bf16x8 b0[4], b1[4];
            LOADB_V(b0, 0)
#pragma unroll
            for (int k2 = 0; k2 < 4; ++k2) {
                LOADB_V(b1, k2 * 2 + 1)
                MFMA_STEP4(b0, k2 * 2)
                if (k2 < 3) { LOADB_V(b0, k2 * 2 + 2) }
                MFMA_STEP4(b1, k2 * 2 + 1)
            }
        }
        __syncthreads();   // A reads done; muL visible; reuse A as bf16 D-tile
        const int g = lane >> 4;
#pragma unroll
        for (int i = 0; i < 4; ++i) {
            const int col0 = (w * 4 + i) * 16 + g * 4;
            float4 cs = *(const float4*)(csumV + col0);
            float4 pr = *(const float4*)(preV + col0);
#pragma unroll
            for (int m = 0; m < 4; ++m) {
                const int rl = m * 16 + (lane & 15);
                float mu = muL[rl], rs = rsL[rl];
                uint2 r;
                r.x = (unsigned)f2bf(rs * (acc[i][m][0] - mu * cs.x) + pr.x) |
                      ((unsigned)f2bf(rs * (acc[i][m][1] - mu * cs.y) + pr.y) << 16);
                r.y = (unsigned)f2bf(rs * (acc[i][m][2] - mu * cs.z) + pr.z) |
                      ((unsigned)f2bf(rs * (acc[i][m][3] - mu * cs.w) + pr.w) << 16);
                *(uint2*)&A[rl * 264 + col0] = r;
            }
        }
        __syncthreads();
        {
            // head-major store: value[h][B*NV][32ch]
            const int pix = threadIdx.x >> 2;
            const int chunk = threadIdx.x & 3;
#pragma unroll
            for (int h = 0; h < 8; ++h) {
                *(uint4*)(value + ((size_t)h * VPLANE + (m0 + pix)) * 32 + chunk * 8) =
                    *(uint4*)&A[pix * 264 + h * 32 + chunk * 8];
            }
        }
    } else {
        // ---- qoff path (LDS-free GEMM; planar samples stores) ----
        float* DlA = (float*)A;
        const int lrow = lane & 15, g = lane >> 4, lk = g * 8;
        const float4* qrow = (const float4*)(query + (size_t)(m0 + w * 16 + lrow) * 256) + g * 2;
        f32x4 acc[6];
#pragma unroll
        for (int i = 0; i < 6; ++i) acc[i] = (f32x4){0.f, 0.f, 0.f, 0.f};
        float s = 0.f, sq = 0.f;
#pragma unroll
        for (int kk = 0; kk < 8; ++kk) {
            float4 xa = qrow[kk * 8];
            float4 xb = qrow[kk * 8 + 1];
            s  += xa.x + xa.y + xa.z + xa.w + xb.x + xb.y + xb.z + xb.w;
            sq += xa.x * xa.x + xa.y * xa.y + xa.z * xa.z + xa.w * xa.w +
                  xb.x * xb.x + xb.y * xb.y + xb.z * xb.z + xb.w * xb.w;
            union { bf16x8 v; unsigned short u[8]; } af;
            af.u[0] = f2bf(xa.x); af.u[1] = f2bf(xa.y); af.u[2] = f2bf(xa.z); af.u[3] = f2bf(xa.w);
            af.u[4] = f2bf(xb.x); af.u[5] = f2bf(xb.y); af.u[6] = f2bf(xb.z); af.u[7] = f2bf(xb.w);
            bf16x8 b[6];
#pragma unroll
            for (int i = 0; i < 6; ++i)
                b[i] = *(const bf16x8*)(WtC + (size_t)(i * 16 + lrow) * 256 + kk * 32 + lk);
#pragma unroll
            for (int i = 0; i < 6; ++i) acc[i] = mfma16(b[i], af.v, acc[i]);
        }
        s += __shfl_xor(s, 16); sq += __shfl_xor(sq, 16);
        s += __shfl_xor(s, 32); sq += __shfl_xor(sq, 32);
        if (lane < 16) {
            float mu = s * 0.00390625f;
            muL[w * 16 + lane] = mu;
            rsL[w * 16 + lane] = rsqrtf(sq * 0.00390625f - mu * mu + 1e-6f);
        }
        float* Dl = DlA + w * 1600;
#pragma unroll
        for (int i = 0; i < 6; ++i) {
            *(float4*)&Dl[lrow * 100 + i * 16 + g * 4] =
                make_float4(acc[i][0], acc[i][1], acc[i][2], acc[i][3]);
        }
        __syncthreads();
#pragma unroll
        for (int it = 0; it < 2; ++it) {
            int idx = it * 64 + lane;     // 16 rows x 8 heads
            int rl = idx >> 3;
            int h = idx & 7;
            int row = m0 + w * 16 + rl;
            float mu = muL[w * 16 + rl], rs = rsL[w * 16 + rl];
            float rx = refpt[(size_t)row * 2 + 0] * 128.f - 0.5f;
            float ry = refpt[(size_t)row * 2 + 1] * 128.f - 0.5f;
            float l0 = rs * (Dl[rl * 100 + 64 + h * 4 + 0] - mu * csumC[64 + h * 4 + 0]) + preC[64 + h * 4 + 0];
            float l1 = rs * (Dl[rl * 100 + 64 + h * 4 + 1] - mu * csumC[64 + h * 4 + 1]) + preC[64 + h * 4 + 1];
            float l2 = rs * (Dl[rl * 100 + 64 + h * 4 + 2] - mu * csumC[64 + h * 4 + 2]) + preC[64 + h * 4 + 2];
            float l3 = rs * (Dl[rl * 100 + 64 + h * 4 + 3] - mu * csumC[64 + h * 4 + 3]) + preC[64 + h * 4 + 3];
            float mx = fmaxf(fmaxf(l0, l1), fmaxf(l2, l3));
            float e0 = __expf(l0 - mx), e1 = __expf(l1 - mx);
            float e2 = __expf(l2 - mx), e3 = __expf(l3 - mx);
            float inv = 1.f / (e0 + e1 + e2 + e3);
            float ww[4] = {e0 * inv, e1 * inv, e2 * inv, e3 * inv};
            size_t trow = (size_t)row * 8 + h;
#pragma unroll
            for (int p = 0; p < 4; ++p) {
                float ox = rs * (Dl[rl * 100 + h * 8 + p * 2 + 0] - mu * csumC[h * 8 + p * 2 + 0]) + preC[h * 8 + p * 2 + 0];
                float oy = rs * (Dl[rl * 100 + h * 8 + p * 2 + 1] - mu * csumC[h * 8 + p * 2 + 1]) + preC[h * 8 + p * 2 + 1];
                samples[(size_t)p * SAMPN + trow] = make_float4(rx + ox, ry + oy, ww[p], 0.f);
            }
        }
    }
}

// ---------------- standalone gather (R11 structure + bucketed order + head-major taps) ----------------
// 4 lanes per (q,h); no LDS, no barrier; all 20 loads independent -> deep in flight.
__global__ __launch_bounds__(256) void k_gather(
    const unsigned short* __restrict__ value, const float4* __restrict__ samples,
    const int* __restrict__ perm, unsigned short* __restrict__ accb) {
    const int tid = blockIdx.x * 256 + threadIdx.x;
    const int sub = tid & 3;
    const int t = tid >> 2;          // slot*8 + h
    const int h = t & 7;
    const int slot = t >> 3;
    const int q = perm[slot];
    const int b = q >> 14;
    const unsigned short* vb =
        value + ((size_t)h * VPLANE + ((size_t)b << 14)) * 32 + sub * 8;
    const size_t trow = (size_t)q * 8 + h;
    float a0 = 0.f, a1 = 0.f, a2 = 0.f, a3 = 0.f;
    float a4 = 0.f, a5 = 0.f, a6 = 0.f, a7 = 0.f;
#pragma unroll
    for (int p = 0; p < 4; ++p) {
        float4 s = samples[(size_t)p * SAMPN + trow];
        float xf = floorf(s.x), yf = floorf(s.y);
        float fx = s.x - xf, fy = s.y - yf;
        int x0 = (int)xf, y0 = (int)yf;
        int x1 = x0 + 1, y1 = y0 + 1;
        float wgt = s.z;
        bool bx0 = (unsigned)x0 < 128u, bx1 = (unsigned)x1 < 128u;
        bool by0 = (unsigned)y0 < 128u, by1 = (unsigned)y1 < 128u;
        float wt[4];
        wt[0] = (bx0 && by0) ? (1.f - fx) * (1.f - fy) * wgt : 0.f;
        wt[1] = (bx1 && by0) ? fx * (1.f - fy) * wgt : 0.f;
        wt[2] = (bx0 && by1) ? (1.f - fx) * fy * wgt : 0.f;
        wt[3] = (bx1 && by1) ? fx * fy * wgt : 0.f;
        int xc0 = min(max(x0, 0), 127), xc1 = min(max(x1, 0), 127);
        int yc0 = min(max(y0, 0), 127), yc1 = min(max(y1, 0), 127);
        int pix[4];
        pix[0] = yc0 * 128 + xc0; pix[1] = yc0 * 128 + xc1;
        pix[2] = yc1 * 128 + xc0; pix[3] = yc1 * 128 + xc1;
#pragma unroll
        for (int tp = 0; tp < 4; ++tp) {
            uint4 u = *(const uint4*)(vb + (size_t)pix[tp] * 32);
            float wq = wt[tp];
            a0 = fmaf(wq, blo(u.x), a0); a1 = fmaf(wq, bhi(u.x), a1);
            a2 = fmaf(wq, blo(u.y), a2); a3 = fmaf(wq, bhi(u.y), a3);
            a4 = fmaf(wq, blo(u.z), a4); a5 = fmaf(wq, bhi(u.z), a5);
            a6 = fmaf(wq, blo(u.w), a6); a7 = fmaf(wq, bhi(u.w), a7);
        }
    }
    uint4 r;
    r.x = (unsigned)f2bf(a0) | ((unsigned)f2bf(a1) << 16);
    r.y = (unsigned)f2bf(a2) | ((unsigned)f2bf(a3) << 16);
    r.z = (unsigned)f2bf(a4) | ((unsigned)f2bf(a5) << 16);
    r.w = (unsigned)f2bf(a6) | ((unsigned)f2bf(a7) << 16);
    *(uint4*)(accb + (size_t)q * 256 + h * 32 + sub * 8) = r;
}

// ---------------- out GEMM (M=64) + bias + gated residual ----------------
__global__ __launch_bounds__(256, 4) void k_out(
    const unsigned short* __restrict__ accb, const unsigned short* __restrict__ WtO,
    const float* __restrict__ b_out, const float* __restrict__ gamma,
    const float* __restrict__ query, float* __restrict__ out) {
    __shared__ unsigned short A[64 * 264];
    const int m0 = blockIdx.x * 64;
    STAGE_A64(accb)
    __syncthreads();
    const int lane = threadIdx.x & 63;
    const int w = threadIdx.x >> 6;
    const int lrow = lane & 15, lk = (lane >> 4) * 8;
    f32x4 acc[4][4];
#pragma unroll
    for (int i = 0; i < 4; ++i)
#pragma unroll
        for (int m = 0; m < 4; ++m) acc[i][m] = (f32x4){0.f, 0.f, 0.f, 0.f};
#define LOADB_O(dst, kk)                                                              \
    _Pragma("unroll") for (int i = 0; i < 4; ++i) dst[i] =                            \
        *(const bf16x8*)(WtO + (size_t)((w * 4 + i) * 16 + lrow) * 256 + (kk) * 32 + lk);
    {
        bf16x8 b0[4], b1[4];
        LOADB_O(b0, 0)
#pragma unroll
        for (int k2 = 0; k2 < 4; ++k2) {
            LOADB_O(b1, k2 * 2 + 1)
            MFMA_STEP4(b0, k2 * 2)
            if (k2 < 3) { LOADB_O(b0, k2 * 2 + 2) }
            MFMA_STEP4(b1, k2 * 2 + 1)
        }
    }
    const int g = lane >> 4;
    float4 bo[4], gm[4];
#pragma unroll
    for (int i = 0; i < 4; ++i) {
        bo[i] = *(const float4*)(b_out + (w * 4 + i) * 16 + g * 4);
        gm[i] = *(const float4*)(gamma + (w * 4 + i) * 16 + g * 4);
    }
#pragma unroll
    for (int m = 0; m < 4; ++m) {
        const size_t row = (size_t)(m0 + m * 16 + (lane & 15));
#pragma unroll
        for (int i = 0; i < 4; ++i) {
            const int col0 = (w * 4 + i) * 16 + g * 4;
            float4 q = *(const float4*)(query + row * 256 + col0);
            float4 o;
            o.x = q.x + gm[i].x * (acc[i][m][0] + bo[i].x);
            o.y = q.y + gm[i].y * (acc[i][m][1] + bo[i].y);
            o.z = q.z + gm[i].z * (acc[i][m][2] + bo[i].z);
            o.w = q.w + gm[i].w * (acc[i][m][3] + bo[i].w);
            *(float4*)(out + row * 256 + col0) = o;
        }
    }
}

extern "C" void kernel_launch(void* const* d_in, const int* in_sizes, int n_in,
                              void* d_out, int out_size, void* d_ws, size_t ws_size,
                              hipStream_t stream) {
    const float* query    = (const float*)d_in[0];
    const float* feat     = (const float*)d_in[1];
    const float* refpt    = (const float*)d_in[2];
    const float* qn_scale = (const float*)d_in[5];
    const float* qn_bias  = (const float*)d_in[6];
    const float* fn_scale = (const float*)d_in[7];
    const float* fn_bias  = (const float*)d_in[8];
    const float* W_value  = (const float*)d_in[9];
    const float* b_value  = (const float*)d_in[10];
    const float* W_off    = (const float*)d_in[11];
    const float* b_off    = (const float*)d_in[12];
    const float* W_attn   = (const float*)d_in[13];
    const float* b_attn   = (const float*)d_in[14];
    const float* W_out    = (const float*)d_in[15];
    const float* b_out    = (const float*)d_in[16];
    const float* gamma    = (const float*)d_in[17];
    float* out = (float*)d_out;

    char* ws = (char*)d_ws;
    unsigned short* WtV   = (unsigned short*)(ws);            // 128 KB
    unsigned short* WtO   = (unsigned short*)(ws + 131072);   // 128 KB
    unsigned short* WtC   = (unsigned short*)(ws + 262144);   // 48 KB -> 311296
    float* csumV = (float*)(ws + 311296);
    float* preV  = (float*)(ws + 312320);
    float* csumC = (float*)(ws + 313344);
    float* preC  = (float*)(ws + 313856);                     // -> 314368
    int* hist    = (int*)(ws + 314368);                       // 4 KB
    int* basep   = (int*)(ws + 318464);                       // 4 KB
    int* cursor  = (int*)(ws + 322560);                       // 4 KB
    int* perm    = (int*)(ws + 326656);                       // 256 KB -> 588800
    unsigned short* value = (unsigned short*)(ws + 655360);                  // 32 MB
    float4* samples       = (float4*)(ws + 655360 + 33554432);               // 32 MB
    unsigned short* accb  = (unsigned short*)(ws + 655360 + 2 * 33554432);   // 32 MB

    hipMemsetAsync(ws + 314368, 0, 12288, stream);
    hipLaunchKernelGGL(k_prep, dim3(613), dim3(256), 0, stream,
                       W_value, W_off, W_attn, W_out,
                       fn_scale, fn_bias, qn_scale, qn_bias,
                       b_value, b_off, b_attn,
                       WtV, WtC, WtO, csumV, preV, csumC, preC);
    hipLaunchKernelGGL(k_hist, dim3(256), dim3(256), 0, stream, refpt, hist);
    hipLaunchKernelGGL(k_scan, dim3(1), dim3(256), 0, stream, hist, basep, cursor);
    hipLaunchKernelGGL(k_perm, dim3(256), dim3(256), 0, stream, refpt, cursor, perm);
    hipLaunchKernelGGL(k_mlp, dim3(2048), dim3(256), 0, stream,
                       feat, csumV, preV, WtV, value,
                       query, refpt, csumC, preC, WtC, samples);
    hipLaunchKernelGGL(k_gather, dim3(8192), dim3(256), 0, stream,
                       value, samples, perm, accb);
    hipLaunchKernelGGL(k_out, dim3(1024), dim3(256), 0, stream,
                       accb, WtO, b_out, gamma, query, out);
}

// Round 19
// 175.925 us; speedup vs baseline: 1.1121x; 1.1121x over previous
//
#include <hip/hip_runtime.h>

#define NQ 16384
#define NV 16384
#define DMODEL 256
#define SAMPN (4 * 16384 * 8)   // one plane: B*NQ*HEADS float4s
#define VPLANE 65536            // value plane: B*NV pixels (head-major layout)

typedef __bf16 bf16x8 __attribute__((ext_vector_type(8)));
typedef float f32x4 __attribute__((ext_vector_type(4)));

__device__ __forceinline__ unsigned short f2bf(float x) {
    union { float f; unsigned int u; } v; v.f = x;
    unsigned int r = v.u + 0x7fff + ((v.u >> 16) & 1);
    return (unsigned short)(r >> 16);
}
__device__ __forceinline__ float blo(unsigned int u) {
    union { unsigned int u; float f; } v; v.u = u << 16; return v.f;
}
__device__ __forceinline__ float bhi(unsigned int u) {
    union { unsigned int u; float f; } v; v.u = u & 0xFFFF0000u; return v.f;
}
__device__ __forceinline__ f32x4 mfma16(bf16x8 a, bf16x8 b, f32x4 c) {
    return __builtin_amdgcn_mfma_f32_16x16x32_bf16(a, b, c, 0, 0, 0);
}

// ---------------- prep: scaled transposed weights + LN-fold constants ----------------
__global__ __launch_bounds__(256) void k_prep(
    const float* __restrict__ Wv, const float* __restrict__ Woff,
    const float* __restrict__ Wattn, const float* __restrict__ Wout,
    const float* __restrict__ fns, const float* __restrict__ fnb,
    const float* __restrict__ qns, const float* __restrict__ qnb,
    const float* __restrict__ b_value, const float* __restrict__ b_off,
    const float* __restrict__ b_attn,
    unsigned short* __restrict__ WtV, unsigned short* __restrict__ WtC,
    unsigned short* __restrict__ WtO,
    float* __restrict__ csumV, float* __restrict__ preV,
    float* __restrict__ csumC, float* __restrict__ preC) {
    const int blk = blockIdx.x;
    if (blk < 608) {
        int t = blk * 256 + threadIdx.x;
        if (t < 65536) { int n = t >> 8, k = t & 255; WtV[t] = f2bf(fns[k] * Wv[k * 256 + n]); return; }
        t -= 65536;
        if (t < 65536) { int n = t >> 8, k = t & 255; WtO[t] = f2bf(Wout[k * 256 + n]); return; }
        t -= 65536;
        if (t < 24576) {
            int j = t >> 8, k = t & 255;
            float w = (j < 64) ? Woff[k * 64 + j] : Wattn[k * 32 + (j - 64)];
            WtC[j * 256 + k] = f2bf(qns[k] * w);
        }
        return;
    }
    if (blk < 612) {   // csumV / preV
        __shared__ float sCS[4][64], sPR[4][64];
        const int nl = threadIdx.x & 63;
        const int n = (blk - 608) * 64 + nl;
        const int kp = threadIdx.x >> 6;
        float cs = 0.f, pr = 0.f;
        for (int k = kp * 64; k < kp * 64 + 64; ++k) {
            float w = Wv[k * 256 + n];
            cs += fns[k] * w;
            pr += fnb[k] * w;
        }
        sCS[kp][nl] = cs; sPR[kp][nl] = pr;
        __syncthreads();
        if (threadIdx.x < 64) {
            int nn = (blk - 608) * 64 + threadIdx.x;
            csumV[nn] = sCS[0][threadIdx.x] + sCS[1][threadIdx.x] + sCS[2][threadIdx.x] + sCS[3][threadIdx.x];
            preV[nn] = sPR[0][threadIdx.x] + sPR[1][threadIdx.x] + sPR[2][threadIdx.x] + sPR[3][threadIdx.x]
                       + b_value[nn];
        }
        return;
    }
    {   // blk == 612: csumC / preC
        __shared__ float sCS[2][96], sPR[2][96];
        const int t = threadIdx.x;
        if (t < 192) {
            const int n = t % 96;
            const int kp = t / 96;
            float cs = 0.f, pr = 0.f;
            for (int k = kp * 128; k < kp * 128 + 128; ++k) {
                float w = (n < 64) ? Woff[k * 64 + n] : Wattn[k * 32 + (n - 64)];
                cs += qns[k] * w;
                pr += qnb[k] * w;
            }
            sCS[kp][n] = cs; sPR[kp][n] = pr;
        }
        __syncthreads();
        if (t < 96) {
            csumC[t] = sCS[0][t] + sCS[1][t];
            preC[t] = sPR[0][t] + sPR[1][t] + ((t < 64) ? b_off[t] : b_attn[t - 64]);
        }
        return;
    }
}

// Coalesced fp32->bf16 stage (64 rows) + LDS-based row stats (4 threads/row).
#define STAGE_LNSTATS64(srcptr)                                                       \
    {                                                                                 \
        const int t = threadIdx.x;                                                    \
        const float4* src4 = (const float4*)((srcptr) + (size_t)m0 * 256);            \
        _Pragma("unroll 8") for (int i = 0; i < 16; ++i) {                            \
            float4 x = src4[i * 256 + t];                                             \
            const int row = i * 4 + (t >> 6);                                         \
            uint2 pk;                                                                 \
            pk.x = (unsigned)f2bf(x.x) | ((unsigned)f2bf(x.y) << 16);                 \
            pk.y = (unsigned)f2bf(x.z) | ((unsigned)f2bf(x.w) << 16);                 \
            *(uint2*)&A[row * 264 + (t & 63) * 4] = pk;                               \
        }                                                                             \
    }                                                                                 \
    __syncthreads();                                                                  \
    {                                                                                 \
        const int t = threadIdx.x;                                                    \
        const int r = t >> 2, h = t & 3;                                              \
        float s = 0.f, sq = 0.f;                                                      \
        _Pragma("unroll") for (int j = 0; j < 8; ++j) {                               \
            uint4 u = *(const uint4*)&A[r * 264 + h * 64 + j * 8];                    \
            float v0 = blo(u.x), v1 = bhi(u.x), v2 = blo(u.y), v3 = bhi(u.y);         \
            float v4 = blo(u.z), v5 = bhi(u.z), v6 = blo(u.w), v7 = bhi(u.w);         \
            s += v0 + v1 + v2 + v3 + v4 + v5 + v6 + v7;                               \
            sq += v0 * v0 + v1 * v1 + v2 * v2 + v3 * v3 +                             \
                  v4 * v4 + v5 * v5 + v6 * v6 + v7 * v7;                              \
        }                                                                             \
        s += __shfl_xor(s, 1);  sq += __shfl_xor(sq, 1);                              \
        s += __shfl_xor(s, 2);  sq += __shfl_xor(sq, 2);                              \
        if (h == 0) {                                                                 \
            float mu = s * 0.00390625f;                                               \
            muL[r] = mu;                                                              \
            rsL[r] = rsqrtf(sq * 0.00390625f - mu * mu + 1e-6f);                      \
        }                                                                             \
    }

#define MFMA_STEP4(bf, kk)                                                            \
    _Pragma("unroll") for (int m = 0; m < 4; ++m) {                                   \
        bf16x8 a = *(const bf16x8*)&A[(m * 16 + lrow) * 264 + (kk) * 32 + lk];        \
        _Pragma("unroll") for (int i = 0; i < 4; ++i)                                 \
            acc[i][m] = mfma16(bf[i], a, acc[i][m]);                                  \
    }

// ---------------- fused MLP dispatch: even blocks = value-tile, odd = qoff-tile ----------------
__global__ __launch_bounds__(256, 4) void k_mlp(
    const float* __restrict__ feat, const float* __restrict__ csumV,
    const float* __restrict__ preV, const unsigned short* __restrict__ WtV,
    unsigned short* __restrict__ value,
    const float* __restrict__ query, const float* __restrict__ refpt,
    const float* __restrict__ csumC, const float* __restrict__ preC,
    const unsigned short* __restrict__ WtC, float4* __restrict__ samples) {
    __shared__ unsigned short A[64 * 264];
    __shared__ float muL[64], rsL[64];
    const int blk = blockIdx.x;
    const int m0 = (blk >> 1) * 64;
    const int lane = threadIdx.x & 63;
    const int w = threadIdx.x >> 6;

    if ((blk & 1) == 0) {
        // ---- value path (LDS-staged GEMM, LN folded into epilogue) ----
        STAGE_LNSTATS64(feat)
        const int lrow = lane & 15, lk = (lane >> 4) * 8;
        f32x4 acc[4][4];
#pragma unroll
        for (int i = 0; i < 4; ++i)
#pragma unroll
            for (int m = 0; m < 4; ++m) acc[i][m] = (f32x4){0.f, 0.f, 0.f, 0.f};
#define LOADB_V(dst, kk)                                                              \
    _Pragma("unroll") for (int i = 0; i < 4; ++i) dst[i] =                            \
        *(const bf16x8*)(WtV + (size_t)((w * 4 + i) * 16 + lrow) * 256 + (kk) * 32 + lk);
        {
            bf16x8 b0[4], b1[4];
            LOADB_V(b0, 0)
#pragma unroll
            for (int k2 = 0; k2 < 4; ++k2) {
                LOADB_V(b1, k2 * 2 + 1)
                MFMA_STEP4(b0, k2 * 2)
                if (k2 < 3) { LOADB_V(b0, k2 * 2 + 2) }
                MFMA_STEP4(b1, k2 * 2 + 1)
            }
        }
        __syncthreads();   // A reads done; muL visible; reuse A as bf16 D-tile
        const int g = lane >> 4;
#pragma unroll
        for (int i = 0; i < 4; ++i) {
            const int col0 = (w * 4 + i) * 16 + g * 4;
            float4 cs = *(const float4*)(csumV + col0);
            float4 pr = *(const float4*)(preV + col0);
#pragma unroll
            for (int m = 0; m < 4; ++m) {
                const int rl = m * 16 + (lane & 15);
                float mu = muL[rl], rs = rsL[rl];
                uint2 r;
                r.x = (unsigned)f2bf(rs * (acc[i][m][0] - mu * cs.x) + pr.x) |
                      ((unsigned)f2bf(rs * (acc[i][m][1] - mu * cs.y) + pr.y) << 16);
                r.y = (unsigned)f2bf(rs * (acc[i][m][2] - mu * cs.z) + pr.z) |
                      ((unsigned)f2bf(rs * (acc[i][m][3] - mu * cs.w) + pr.w) << 16);
                *(uint2*)&A[rl * 264 + col0] = r;
            }
        }
        __syncthreads();
        {
            // head-major store: value[h][B*NV][32ch]
            const int pix = threadIdx.x >> 2;
            const int chunk = threadIdx.x & 3;
#pragma unroll
            for (int h = 0; h < 8; ++h) {
                *(uint4*)(value + ((size_t)h * VPLANE + (m0 + pix)) * 32 + chunk * 8) =
                    *(uint4*)&A[pix * 264 + h * 32 + chunk * 8];
            }
        }
    } else {
        // ---- qoff path (LDS-free GEMM; planar samples stores) ----
        float* DlA = (float*)A;
        const int lrow = lane & 15, g = lane >> 4, lk = g * 8;
        const float4* qrow = (const float4*)(query + (size_t)(m0 + w * 16 + lrow) * 256) + g * 2;
        f32x4 acc[6];
#pragma unroll
        for (int i = 0; i < 6; ++i) acc[i] = (f32x4){0.f, 0.f, 0.f, 0.f};
        float s = 0.f, sq = 0.f;
#pragma unroll
        for (int kk = 0; kk < 8; ++kk) {
            float4 xa = qrow[kk * 8];
            float4 xb = qrow[kk * 8 + 1];
            s  += xa.x + xa.y + xa.z + xa.w + xb.x + xb.y + xb.z + xb.w;
            sq += xa.x * xa.x + xa.y * xa.y + xa.z * xa.z + xa.w * xa.w +
                  xb.x * xb.x + xb.y * xb.y + xb.z * xb.z + xb.w * xb.w;
            union { bf16x8 v; unsigned short u[8]; } af;
            af.u[0] = f2bf(xa.x); af.u[1] = f2bf(xa.y); af.u[2] = f2bf(xa.z); af.u[3] = f2bf(xa.w);
            af.u[4] = f2bf(xb.x); af.u[5] = f2bf(xb.y); af.u[6] = f2bf(xb.z); af.u[7] = f2bf(xb.w);
            bf16x8 b[6];
#pragma unroll
            for (int i = 0; i < 6; ++i)
                b[i] = *(const bf16x8*)(WtC + (size_t)(i * 16 + lrow) * 256 + kk * 32 + lk);
#pragma unroll
            for (int i = 0; i < 6; ++i) acc[i] = mfma16(b[i], af.v, acc[i]);
        }
        s += __shfl_xor(s, 16); sq += __shfl_xor(sq, 16);
        s += __shfl_xor(s, 32); sq += __shfl_xor(sq, 32);
        if (lane < 16) {
            float mu = s * 0.00390625f;
            muL[w * 16 + lane] = mu;
            rsL[w * 16 + lane] = rsqrtf(sq * 0.00390625f - mu * mu + 1e-6f);
        }
        float* Dl = DlA + w * 1600;
#pragma unroll
        for (int i = 0; i < 6; ++i) {
            *(float4*)&Dl[lrow * 100 + i * 16 + g * 4] =
                make_float4(acc[i][0], acc[i][1], acc[i][2], acc[i][3]);
        }
        __syncthreads();
#pragma unroll
        for (int it = 0; it < 2; ++it) {
            int idx = it * 64 + lane;     // 16 rows x 8 heads
            int rl = idx >> 3;
            int h = idx & 7;
            int row = m0 + w * 16 + rl;
            float mu = muL[w * 16 + rl], rs = rsL[w * 16 + rl];
            float rx = refpt[(size_t)row * 2 + 0] * 128.f - 0.5f;
            float ry = refpt[(size_t)row * 2 + 1] * 128.f - 0.5f;
            float l0 = rs * (Dl[rl * 100 + 64 + h * 4 + 0] - mu * csumC[64 + h * 4 + 0]) + preC[64 + h * 4 + 0];
            float l1 = rs * (Dl[rl * 100 + 64 + h * 4 + 1] - mu * csumC[64 + h * 4 + 1]) + preC[64 + h * 4 + 1];
            float l2 = rs * (Dl[rl * 100 + 64 + h * 4 + 2] - mu * csumC[64 + h * 4 + 2]) + preC[64 + h * 4 + 2];
            float l3 = rs * (Dl[rl * 100 + 64 + h * 4 + 3] - mu * csumC[64 + h * 4 + 3]) + preC[64 + h * 4 + 3];
            float mx = fmaxf(fmaxf(l0, l1), fmaxf(l2, l3));
            float e0 = __expf(l0 - mx), e1 = __expf(l1 - mx);
            float e2 = __expf(l2 - mx), e3 = __expf(l3 - mx);
            float inv = 1.f / (e0 + e1 + e2 + e3);
            float ww[4] = {e0 * inv, e1 * inv, e2 * inv, e3 * inv};
            size_t trow = (size_t)row * 8 + h;
#pragma unroll
            for (int p = 0; p < 4; ++p) {
                float ox = rs * (Dl[rl * 100 + h * 8 + p * 2 + 0] - mu * csumC[h * 8 + p * 2 + 0]) + preC[h * 8 + p * 2 + 0];
                float oy = rs * (Dl[rl * 100 + h * 8 + p * 2 + 1] - mu * csumC[h * 8 + p * 2 + 1]) + preC[h * 8 + p * 2 + 1];
                samples[(size_t)p * SAMPN + trow] = make_float4(rx + ox, ry + oy, ww[p], 0.f);
            }
        }
    }
}

// per-slot gather body: computes 8-channel accumulation for (trow, vb)
#define GATHER_SLOT(svec, aq0, aq1, aq2, aq3, aq4, aq5, aq6, aq7)                     \
    _Pragma("unroll") for (int p = 0; p < 4; ++p) {                                   \
        float4 s = svec[p];                                                           \
        float xf = floorf(s.x), yf = floorf(s.y);                                     \
        float fx = s.x - xf, fy = s.y - yf;                                           \
        int x0 = (int)xf, y0 = (int)yf;                                               \
        int x1 = x0 + 1, y1 = y0 + 1;                                                 \
        float wgt = s.z;                                                              \
        bool bx0 = (unsigned)x0 < 128u, bx1 = (unsigned)x1 < 128u;                    \
        bool by0 = (unsigned)y0 < 128u, by1 = (unsigned)y1 < 128u;                    \
        float wt[4];                                                                  \
        wt[0] = (bx0 && by0) ? (1.f - fx) * (1.f - fy) * wgt : 0.f;                   \
        wt[1] = (bx1 && by0) ? fx * (1.f - fy) * wgt : 0.f;                           \
        wt[2] = (bx0 && by1) ? (1.f - fx) * fy * wgt : 0.f;                           \
        wt[3] = (bx1 && by1) ? fx * fy * wgt : 0.f;                                   \
        int xc0 = min(max(x0, 0), 127), xc1 = min(max(x1, 0), 127);                   \
        int yc0 = min(max(y0, 0), 127), yc1 = min(max(y1, 0), 127);                   \
        int pix[4];                                                                   \
        pix[0] = yc0 * 128 + xc0; pix[1] = yc0 * 128 + xc1;                           \
        pix[2] = yc1 * 128 + xc0; pix[3] = yc1 * 128 + xc1;                           \
        _Pragma("unroll") for (int tp = 0; tp < 4; ++tp) {                            \
            uint4 u = *(const uint4*)(vb + (size_t)pix[tp] * 32);                     \
            float wq = wt[tp];                                                        \
            aq0 = fmaf(wq, blo(u.x), aq0); aq1 = fmaf(wq, bhi(u.x), aq1);             \
            aq2 = fmaf(wq, blo(u.y), aq2); aq3 = fmaf(wq, bhi(u.y), aq3);             \
            aq4 = fmaf(wq, blo(u.z), aq4); aq5 = fmaf(wq, bhi(u.z), aq5);             \
            aq6 = fmaf(wq, blo(u.w), aq6); aq7 = fmaf(wq, bhi(u.w), aq7);             \
        }                                                                             \
    }

// ---------------- fused gather + out GEMM; paired-slot gather for 2x MLP ----------------
__global__ __launch_bounds__(256, 4) void k_gatherout(
    const unsigned short* __restrict__ value, const float4* __restrict__ samples,
    const unsigned short* __restrict__ WtO, const float* __restrict__ b_out,
    const float* __restrict__ gamma, const float* __restrict__ query,
    float* __restrict__ out) {
    __shared__ unsigned short A[64 * 264];
    const int m0 = blockIdx.x * 64;          // global row = b*NQ + q
    const int b = m0 >> 14;
    {
        const int t = threadIdx.x;
        const int h = (t >> 2) & 7;
        const int sub = t & 3;
        const int g = t >> 5;  // 0..7
        const unsigned short* vb =
            value + ((size_t)h * VPLANE + ((size_t)b << 14)) * 32 + sub * 8;
#pragma unroll
        for (int k2 = 0; k2 < 4; ++k2) {
            const int rlA = k2 * 16 + g;
            const int rlB = rlA + 8;
            const size_t trowA = (size_t)(m0 + rlA) * 8 + h;
            const size_t trowB = (size_t)(m0 + rlB) * 8 + h;
            float4 sA[4], sB[4];
#pragma unroll
            for (int p = 0; p < 4; ++p) {
                sA[p] = samples[(size_t)p * SAMPN + trowA];
                sB[p] = samples[(size_t)p * SAMPN + trowB];
            }
            float a0 = 0.f, a1 = 0.f, a2 = 0.f, a3 = 0.f;
            float a4 = 0.f, a5 = 0.f, a6 = 0.f, a7 = 0.f;
            float c0 = 0.f, c1 = 0.f, c2 = 0.f, c3 = 0.f;
            float c4 = 0.f, c5 = 0.f, c6 = 0.f, c7 = 0.f;
            GATHER_SLOT(sA, a0, a1, a2, a3, a4, a5, a6, a7)
            GATHER_SLOT(sB, c0, c1, c2, c3, c4, c5, c6, c7)
            uint4 rA, rB;
            rA.x = (unsigned)f2bf(a0) | ((unsigned)f2bf(a1) << 16);
            rA.y = (unsigned)f2bf(a2) | ((unsigned)f2bf(a3) << 16);
            rA.z = (unsigned)f2bf(a4) | ((unsigned)f2bf(a5) << 16);
            rA.w = (unsigned)f2bf(a6) | ((unsigned)f2bf(a7) << 16);
            rB.x = (unsigned)f2bf(c0) | ((unsigned)f2bf(c1) << 16);
            rB.y = (unsigned)f2bf(c2) | ((unsigned)f2bf(c3) << 16);
            rB.z = (unsigned)f2bf(c4) | ((unsigned)f2bf(c5) << 16);
            rB.w = (unsigned)f2bf(c6) | ((unsigned)f2bf(c7) << 16);
            *(uint4*)&A[rlA * 264 + h * 32 + sub * 8] = rA;
            *(uint4*)&A[rlB * 264 + h * 32 + sub * 8] = rB;
        }
    }
    __syncthreads();
    const int lane = threadIdx.x & 63;
    const int w = threadIdx.x >> 6;
    const int lrow = lane & 15, lk = (lane >> 4) * 8;
    f32x4 acc[4][4];
#pragma unroll
    for (int i = 0; i < 4; ++i)
#pragma unroll
        for (int m = 0; m < 4; ++m) acc[i][m] = (f32x4){0.f, 0.f, 0.f, 0.f};
#define LOADB_O(dst, kk)                                                              \
    _Pragma("unroll") for (int i = 0; i < 4; ++i) dst[i] =                            \
        *(const bf16x8*)(WtO + (size_t)((w * 4 + i) * 16 + lrow) * 256 + (kk) * 32 + lk);
    {
        bf16x8 b0[4], b1[4];
        LOADB_O(b0, 0)
#pragma unroll
        for (int k2 = 0; k2 < 4; ++k2) {
            LOADB_O(b1, k2 * 2 + 1)
            MFMA_STEP4(b0, k2 * 2)
            if (k2 < 3) { LOADB_O(b0, k2 * 2 + 2) }
            MFMA_STEP4(b1, k2 * 2 + 1)
        }
    }
    const int g = lane >> 4;
    float4 bo[4], gm[4];
#pragma unroll
    for (int i = 0; i < 4; ++i) {
        bo[i] = *(const float4*)(b_out + (w * 4 + i) * 16 + g * 4);
        gm[i] = *(const float4*)(gamma + (w * 4 + i) * 16 + g * 4);
    }
#pragma unroll
    for (int m = 0; m < 4; ++m) {
        const size_t row = (size_t)(m0 + m * 16 + (lane & 15));
#pragma unroll
        for (int i = 0; i < 4; ++i) {
            const int col0 = (w * 4 + i) * 16 + g * 4;
            float4 q = *(const float4*)(query + row * 256 + col0);
            float4 o;
            o.x = q.x + gm[i].x * (acc[i][m][0] + bo[i].x);
            o.y = q.y + gm[i].y * (acc[i][m][1] + bo[i].y);
            o.z = q.z + gm[i].z * (acc[i][m][2] + bo[i].z);
            o.w = q.w + gm[i].w * (acc[i][m][3] + bo[i].w);
            *(float4*)(out + row * 256 + col0) = o;
        }
    }
}

extern "C" void kernel_launch(void* const* d_in, const int* in_sizes, int n_in,
                              void* d_out, int out_size, void* d_ws, size_t ws_size,
                              hipStream_t stream) {
    const float* query    = (const float*)d_in[0];
    const float* feat     = (const float*)d_in[1];
    const float* refpt    = (const float*)d_in[2];
    const float* qn_scale = (const float*)d_in[5];
    const float* qn_bias  = (const float*)d_in[6];
    const float* fn_scale = (const float*)d_in[7];
    const float* fn_bias  = (const float*)d_in[8];
    const float* W_value  = (const float*)d_in[9];
    const float* b_value  = (const float*)d_in[10];
    const float* W_off    = (const float*)d_in[11];
    const float* b_off    = (const float*)d_in[12];
    const float* W_attn   = (const float*)d_in[13];
    const float* b_attn   = (const float*)d_in[14];
    const float* W_out    = (const float*)d_in[15];
    const float* b_out    = (const float*)d_in[16];
    const float* gamma    = (const float*)d_in[17];
    float* out = (float*)d_out;

    char* ws = (char*)d_ws;
    unsigned short* WtV   = (unsigned short*)(ws);            // 128 KB
    unsigned short* WtO   = (unsigned short*)(ws + 131072);   // 128 KB
    unsigned short* WtC   = (unsigned short*)(ws + 262144);   // 48 KB -> 311296
    float* csumV = (float*)(ws + 311296);
    float* preV  = (float*)(ws + 312320);
    float* csumC = (float*)(ws + 313344);
    float* preC  = (float*)(ws + 313856);
    unsigned short* value = (unsigned short*)(ws + 315392);   // 32 MB (8 head planes)
    float4* samples       = (float4*)(ws + 315392 + 33554432); // 32 MB (4 planes)

    hipLaunchKernelGGL(k_prep, dim3(613), dim3(256), 0, stream,
                       W_value, W_off, W_attn, W_out,
                       fn_scale, fn_bias, qn_scale, qn_bias,
                       b_value, b_off, b_attn,
                       WtV, WtC, WtO, csumV, preV, csumC, preC);
    hipLaunchKernelGGL(k_mlp, dim3(2048), dim3(256), 0, stream,
                       feat, csumV, preV, WtV, value,
                       query, refpt, csumC, preC, WtC, samples);
    hipLaunchKernelGGL(k_gatherout, dim3(1024), dim3(256), 0, stream,
                       value, samples, WtO, b_out, gamma, query, out);
}

// Round 20
// 163.170 us; speedup vs baseline: 1.1990x; 1.0782x over previous
//
#include <hip/hip_runtime.h>

#define NQ 16384
#define NV 16384
#define DMODEL 256
#define SAMPN (4 * 16384 * 8)   // one plane: B*NQ*HEADS float4s
#define VPLANE 65536            // value plane: B*NV pixels (head-major layout)

typedef __bf16 bf16x8 __attribute__((ext_vector_type(8)));
typedef float f32x4 __attribute__((ext_vector_type(4)));

__device__ __forceinline__ unsigned short f2bf(float x) {
    union { float f; unsigned int u; } v; v.f = x;
    unsigned int r = v.u + 0x7fff + ((v.u >> 16) & 1);
    return (unsigned short)(r >> 16);
}
__device__ __forceinline__ float blo(unsigned int u) {
    union { unsigned int u; float f; } v; v.u = u << 16; return v.f;
}
__device__ __forceinline__ float bhi(unsigned int u) {
    union { unsigned int u; float f; } v; v.u = u & 0xFFFF0000u; return v.f;
}
__device__ __forceinline__ f32x4 mfma16(bf16x8 a, bf16x8 b, f32x4 c) {
    return __builtin_amdgcn_mfma_f32_16x16x32_bf16(a, b, c, 0, 0, 0);
}

// ---------------- prep: scaled transposed weights + LN-fold constants ----------------
__global__ __launch_bounds__(256) void k_prep(
    const float* __restrict__ Wv, const float* __restrict__ Woff,
    const float* __restrict__ Wattn, const float* __restrict__ Wout,
    const float* __restrict__ fns, const float* __restrict__ fnb,
    const float* __restrict__ qns, const float* __restrict__ qnb,
    const float* __restrict__ b_value, const float* __restrict__ b_off,
    const float* __restrict__ b_attn,
    unsigned short* __restrict__ WtV, unsigned short* __restrict__ WtC,
    unsigned short* __restrict__ WtO,
    float* __restrict__ csumV, float* __restrict__ preV,
    float* __restrict__ csumC, float* __restrict__ preC) {
    const int blk = blockIdx.x;
    if (blk < 608) {
        int t = blk * 256 + threadIdx.x;
        if (t < 65536) { int n = t >> 8, k = t & 255; WtV[t] = f2bf(fns[k] * Wv[k * 256 + n]); return; }
        t -= 65536;
        if (t < 65536) { int n = t >> 8, k = t & 255; WtO[t] = f2bf(Wout[k * 256 + n]); return; }
        t -= 65536;
        if (t < 24576) {
            int j = t >> 8, k = t & 255;
            float w = (j < 64) ? Woff[k * 64 + j] : Wattn[k * 32 + (j - 64)];
            WtC[j * 256 + k] = f2bf(qns[k] * w);
        }
        return;
    }
    if (blk < 612) {   // csumV / preV
        __shared__ float sCS[4][64], sPR[4][64];
        const int nl = threadIdx.x & 63;
        const int n = (blk - 608) * 64 + nl;
        const int kp = threadIdx.x >> 6;
        float cs = 0.f, pr = 0.f;
        for (int k = kp * 64; k < kp * 64 + 64; ++k) {
            float w = Wv[k * 256 + n];
            cs += fns[k] * w;
            pr += fnb[k] * w;
        }
        sCS[kp][nl] = cs; sPR[kp][nl] = pr;
        __syncthreads();
        if (threadIdx.x < 64) {
            int nn = (blk - 608) * 64 + threadIdx.x;
            csumV[nn] = sCS[0][threadIdx.x] + sCS[1][threadIdx.x] + sCS[2][threadIdx.x] + sCS[3][threadIdx.x];
            preV[nn] = sPR[0][threadIdx.x] + sPR[1][threadIdx.x] + sPR[2][threadIdx.x] + sPR[3][threadIdx.x]
                       + b_value[nn];
        }
        return;
    }
    {   // blk == 612: csumC / preC
        __shared__ float sCS[2][96], sPR[2][96];
        const int t = threadIdx.x;
        if (t < 192) {
            const int n = t % 96;
            const int kp = t / 96;
            float cs = 0.f, pr = 0.f;
            for (int k = kp * 128; k < kp * 128 + 128; ++k) {
                float w = (n < 64) ? Woff[k * 64 + n] : Wattn[k * 32 + (n - 64)];
                cs += qns[k] * w;
                pr += qnb[k] * w;
            }
            sCS[kp][n] = cs; sPR[kp][n] = pr;
        }
        __syncthreads();
        if (t < 96) {
            csumC[t] = sCS[0][t] + sCS[1][t];
            preC[t] = sPR[0][t] + sPR[1][t] + ((t < 64) ? b_off[t] : b_attn[t - 64]);
        }
        return;
    }
}

// Coalesced fp32->bf16 stage (64 rows) + LDS-based row stats (4 threads/row).
#define STAGE_LNSTATS64(srcptr)                                                       \
    {                                                                                 \
        const int t = threadIdx.x;                                                    \
        const float4* src4 = (const float4*)((srcptr) + (size_t)m0 * 256);            \
        _Pragma("unroll 8") for (int i = 0; i < 16; ++i) {                            \
            float4 x = src4[i * 256 + t];                                             \
            const int row = i * 4 + (t >> 6);                                         \
            uint2 pk;                                                                 \
            pk.x = (unsigned)f2bf(x.x) | ((unsigned)f2bf(x.y) << 16);                 \
            pk.y = (unsigned)f2bf(x.z) | ((unsigned)f2bf(x.w) << 16);                 \
            *(uint2*)&A[row * 264 + (t & 63) * 4] = pk;                               \
        }                                                                             \
    }                                                                                 \
    __syncthreads();                                                                  \
    {                                                                                 \
        const int t = threadIdx.x;                                                    \
        const int r = t >> 2, h = t & 3;                                              \
        float s = 0.f, sq = 0.f;                                                      \
        _Pragma("unroll") for (int j = 0; j < 8; ++j) {                               \
            uint4 u = *(const uint4*)&A[r * 264 + h * 64 + j * 8];                    \
            float v0 = blo(u.x), v1 = bhi(u.x), v2 = blo(u.y), v3 = bhi(u.y);         \
            float v4 = blo(u.z), v5 = bhi(u.z), v6 = blo(u.w), v7 = bhi(u.w);         \
            s += v0 + v1 + v2 + v3 + v4 + v5 + v6 + v7;                               \
            sq += v0 * v0 + v1 * v1 + v2 * v2 + v3 * v3 +                             \
                  v4 * v4 + v5 * v5 + v6 * v6 + v7 * v7;                              \
        }                                                                             \
        s += __shfl_xor(s, 1);  sq += __shfl_xor(sq, 1);                              \
        s += __shfl_xor(s, 2);  sq += __shfl_xor(sq, 2);                              \
        if (h == 0) {                                                                 \
            float mu = s * 0.00390625f;                                               \
            muL[r] = mu;                                                              \
            rsL[r] = rsqrtf(sq * 0.00390625f - mu * mu + 1e-6f);                      \
        }                                                                             \
    }

#define MFMA_STEP4(bf, kk)                                                            \
    _Pragma("unroll") for (int m = 0; m < 4; ++m) {                                   \
        bf16x8 a = *(const bf16x8*)&A[(m * 16 + lrow) * 264 + (kk) * 32 + lk];        \
        _Pragma("unroll") for (int i = 0; i < 4; ++i)                                 \
            acc[i][m] = mfma16(bf[i], a, acc[i][m]);                                  \
    }

// ---------------- fused MLP dispatch: even blocks = value-tile, odd = qoff-tile ----------------
__global__ __launch_bounds__(256, 4) void k_mlp(
    const float* __restrict__ feat, const float* __restrict__ csumV,
    const float* __restrict__ preV, const unsigned short* __restrict__ WtV,
    unsigned short* __restrict__ value,
    const float* __restrict__ query, const float* __restrict__ refpt,
    const float* __restrict__ csumC, const float* __restrict__ preC,
    const unsigned short* __restrict__ WtC, float4* __restrict__ samples) {
    __shared__ unsigned short A[64 * 264];
    __shared__ float muL[64], rsL[64];
    const int blk = blockIdx.x;
    const int m0 = (blk >> 1) * 64;
    const int lane = threadIdx.x & 63;
    const int w = threadIdx.x >> 6;

    if ((blk & 1) == 0) {
        // ---- value path (LDS-staged GEMM, LN folded into epilogue) ----
        STAGE_LNSTATS64(feat)
        const int lrow = lane & 15, lk = (lane >> 4) * 8;
        f32x4 acc[4][4];
#pragma unroll
        for (int i = 0; i < 4; ++i)
#pragma unroll
            for (int m = 0; m < 4; ++m) acc[i][m] = (f32x4){0.f, 0.f, 0.f, 0.f};
#define LOADB_V(dst, kk)                                                              \
    _Pragma("unroll") for (int i = 0; i < 4; ++i) dst[i] =                            \
        *(const bf16x8*)(WtV + (size_t)((w * 4 + i) * 16 + lrow) * 256 + (kk) * 32 + lk);
        {
            bf16x8 b0[4], b1[4];
            LOADB_V(b0, 0)
#pragma unroll
            for (int k2 = 0; k2 < 4; ++k2) {
                LOADB_V(b1, k2 * 2 + 1)
                MFMA_STEP4(b0, k2 * 2)
                if (k2 < 3) { LOADB_V(b0, k2 * 2 + 2) }
                MFMA_STEP4(b1, k2 * 2 + 1)
            }
        }
        __syncthreads();   // A reads done; muL visible; reuse A as bf16 D-tile
        const int g = lane >> 4;
#pragma unroll
        for (int i = 0; i < 4; ++i) {
            const int col0 = (w * 4 + i) * 16 + g * 4;
            float4 cs = *(const float4*)(csumV + col0);
            float4 pr = *(const float4*)(preV + col0);
#pragma unroll
            for (int m = 0; m < 4; ++m) {
                const int rl = m * 16 + (lane & 15);
                float mu = muL[rl], rs = rsL[rl];
                uint2 r;
                r.x = (unsigned)f2bf(rs * (acc[i][m][0] - mu * cs.x) + pr.x) |
                      ((unsigned)f2bf(rs * (acc[i][m][1] - mu * cs.y) + pr.y) << 16);
                r.y = (unsigned)f2bf(rs * (acc[i][m][2] - mu * cs.z) + pr.z) |
                      ((unsigned)f2bf(rs * (acc[i][m][3] - mu * cs.w) + pr.w) << 16);
                *(uint2*)&A[rl * 264 + col0] = r;
            }
        }
        __syncthreads();
        {
            // head-major store: value[h][B*NV][32ch]
            const int pix = threadIdx.x >> 2;
            const int chunk = threadIdx.x & 3;
#pragma unroll
            for (int h = 0; h < 8; ++h) {
                *(uint4*)(value + ((size_t)h * VPLANE + (m0 + pix)) * 32 + chunk * 8) =
                    *(uint4*)&A[pix * 264 + h * 32 + chunk * 8];
            }
        }
    } else {
        // ---- qoff path (LDS-free GEMM; planar samples stores) ----
        float* DlA = (float*)A;
        const int lrow = lane & 15, g = lane >> 4, lk = g * 8;
        const float4* qrow = (const float4*)(query + (size_t)(m0 + w * 16 + lrow) * 256) + g * 2;
        f32x4 acc[6];
#pragma unroll
        for (int i = 0; i < 6; ++i) acc[i] = (f32x4){0.f, 0.f, 0.f, 0.f};
        float s = 0.f, sq = 0.f;
#pragma unroll
        for (int kk = 0; kk < 8; ++kk) {
            float4 xa = qrow[kk * 8];
            float4 xb = qrow[kk * 8 + 1];
            s  += xa.x + xa.y + xa.z + xa.w + xb.x + xb.y + xb.z + xb.w;
            sq += xa.x * xa.x + xa.y * xa.y + xa.z * xa.z + xa.w * xa.w +
                  xb.x * xb.x + xb.y * xb.y + xb.z * xb.z + xb.w * xb.w;
            union { bf16x8 v; unsigned short u[8]; } af;
            af.u[0] = f2bf(xa.x); af.u[1] = f2bf(xa.y); af.u[2] = f2bf(xa.z); af.u[3] = f2bf(xa.w);
            af.u[4] = f2bf(xb.x); af.u[5] = f2bf(xb.y); af.u[6] = f2bf(xb.z); af.u[7] = f2bf(xb.w);
            bf16x8 b[6];
#pragma unroll
            for (int i = 0; i < 6; ++i)
                b[i] = *(const bf16x8*)(WtC + (size_t)(i * 16 + lrow) * 256 + kk * 32 + lk);
#pragma unroll
            for (int i = 0; i < 6; ++i) acc[i] = mfma16(b[i], af.v, acc[i]);
        }
        s += __shfl_xor(s, 16); sq += __shfl_xor(sq, 16);
        s += __shfl_xor(s, 32); sq += __shfl_xor(sq, 32);
        if (lane < 16) {
            float mu = s * 0.00390625f;
            muL[w * 16 + lane] = mu;
            rsL[w * 16 + lane] = rsqrtf(sq * 0.00390625f - mu * mu + 1e-6f);
        }
        float* Dl = DlA + w * 1600;
#pragma unroll
        for (int i = 0; i < 6; ++i) {
            *(float4*)&Dl[lrow * 100 + i * 16 + g * 4] =
                make_float4(acc[i][0], acc[i][1], acc[i][2], acc[i][3]);
        }
        __syncthreads();
#pragma unroll
        for (int it = 0; it < 2; ++it) {
            int idx = it * 64 + lane;     // 16 rows x 8 heads
            int rl = idx >> 3;
            int h = idx & 7;
            int row = m0 + w * 16 + rl;
            float mu = muL[w * 16 + rl], rs = rsL[w * 16 + rl];
            float rx = refpt[(size_t)row * 2 + 0] * 128.f - 0.5f;
            float ry = refpt[(size_t)row * 2 + 1] * 128.f - 0.5f;
            float l0 = rs * (Dl[rl * 100 + 64 + h * 4 + 0] - mu * csumC[64 + h * 4 + 0]) + preC[64 + h * 4 + 0];
            float l1 = rs * (Dl[rl * 100 + 64 + h * 4 + 1] - mu * csumC[64 + h * 4 + 1]) + preC[64 + h * 4 + 1];
            float l2 = rs * (Dl[rl * 100 + 64 + h * 4 + 2] - mu * csumC[64 + h * 4 + 2]) + preC[64 + h * 4 + 2];
            float l3 = rs * (Dl[rl * 100 + 64 + h * 4 + 3] - mu * csumC[64 + h * 4 + 3]) + preC[64 + h * 4 + 3];
            float mx = fmaxf(fmaxf(l0, l1), fmaxf(l2, l3));
            float e0 = __expf(l0 - mx), e1 = __expf(l1 - mx);
            float e2 = __expf(l2 - mx), e3 = __expf(l3 - mx);
            float inv = 1.f / (e0 + e1 + e2 + e3);
            float ww[4] = {e0 * inv, e1 * inv, e2 * inv, e3 * inv};
            size_t trow = (size_t)row * 8 + h;
#pragma unroll
            for (int p = 0; p < 4; ++p) {
                float ox = rs * (Dl[rl * 100 + h * 8 + p * 2 + 0] - mu * csumC[h * 8 + p * 2 + 0]) + preC[h * 8 + p * 2 + 0];
                float oy = rs * (Dl[rl * 100 + h * 8 + p * 2 + 1] - mu * csumC[h * 8 + p * 2 + 1]) + preC[h * 8 + p * 2 + 1];
                samples[(size_t)p * SAMPN + trow] = make_float4(rx + ox, ry + oy, ww[p], 0.f);
            }
        }
    }
}

// ---------------- fused gather + out GEMM; 8-lane slots with x-pair tap loads ----------------
// Slot = (q,h) owned by 8 lanes: lanes 0-3 cover pixel xbase, lanes 4-7 cover xbase+1
// (128B contiguous per tap-row => one VMEM instruction covers both x taps).
__global__ __launch_bounds__(256, 4) void k_gatherout(
    const unsigned short* __restrict__ value, const float4* __restrict__ samples,
    const unsigned short* __restrict__ WtO, const float* __restrict__ b_out,
    const float* __restrict__ gamma, const float* __restrict__ query,
    float* __restrict__ out) {
    __shared__ unsigned short A[64 * 264];
    const int m0 = blockIdx.x * 64;          // global row = b*NQ + q
    const int b = m0 >> 14;
    {
        const int t = threadIdx.x;
        const int sub = t & 7;               // lane within slot
        const int h2 = sub >> 2;             // x-half (0: xbase, 1: xbase+1)
        const int h = (t >> 3) & 7;          // head
        const unsigned short* vb = value + ((size_t)h * VPLANE + ((size_t)b << 14)) * 32;
        for (int k = 0; k < 16; ++k) {
            const int rl = k * 4 + (t >> 6); // query row in tile
            const size_t trow = (size_t)(m0 + rl) * 8 + h;
            float a0 = 0.f, a1 = 0.f, a2 = 0.f, a3 = 0.f;
            float a4 = 0.f, a5 = 0.f, a6 = 0.f, a7 = 0.f;
#pragma unroll
            for (int p = 0; p < 4; ++p) {
                float4 s = samples[(size_t)p * SAMPN + trow];
                float xf = floorf(s.x), yf = floorf(s.y);
                float fx = s.x - xf, fy = s.y - yf;
                int x0 = (int)xf, y0 = (int)yf;
                int x1 = x0 + 1, y1 = y0 + 1;
                float wgt = s.z;
                float wx0 = ((unsigned)x0 < 128u) ? (1.f - fx) : 0.f;
                float wx1 = ((unsigned)x1 < 128u) ? fx : 0.f;
                int xbase = min(max(x0, 0), 126);
                int xh = xbase + h2;
                float whx = (xh == x0) ? wx0 : ((xh == x1) ? wx1 : 0.f);
                float wy0 = ((unsigned)y0 < 128u) ? (1.f - fy) : 0.f;
                float wy1 = ((unsigned)y1 < 128u) ? fy : 0.f;
                int yc0 = min(max(y0, 0), 127), yc1 = min(max(y1, 0), 127);
                float w0 = whx * wy0 * wgt;
                float w1 = whx * wy1 * wgt;
                uint4 u0 = *(const uint4*)(vb + (size_t)(yc0 * 128 + xbase) * 32 + sub * 8);
                uint4 u1 = *(const uint4*)(vb + (size_t)(yc1 * 128 + xbase) * 32 + sub * 8);
                a0 = fmaf(w0, blo(u0.x), a0); a1 = fmaf(w0, bhi(u0.x), a1);
                a2 = fmaf(w0, blo(u0.y), a2); a3 = fmaf(w0, bhi(u0.y), a3);
                a4 = fmaf(w0, blo(u0.z), a4); a5 = fmaf(w0, bhi(u0.z), a5);
                a6 = fmaf(w0, blo(u0.w), a6); a7 = fmaf(w0, bhi(u0.w), a7);
                a0 = fmaf(w1, blo(u1.x), a0); a1 = fmaf(w1, bhi(u1.x), a1);
                a2 = fmaf(w1, blo(u1.y), a2); a3 = fmaf(w1, bhi(u1.y), a3);
                a4 = fmaf(w1, blo(u1.z), a4); a5 = fmaf(w1, bhi(u1.z), a5);
                a6 = fmaf(w1, blo(u1.w), a6); a7 = fmaf(w1, bhi(u1.w), a7);
            }
            // combine x-halves: lane sub and sub^4 hold partials for the same 8 channels
            a0 += __shfl_xor(a0, 4); a1 += __shfl_xor(a1, 4);
            a2 += __shfl_xor(a2, 4); a3 += __shfl_xor(a3, 4);
            a4 += __shfl_xor(a4, 4); a5 += __shfl_xor(a5, 4);
            a6 += __shfl_xor(a6, 4); a7 += __shfl_xor(a7, 4);
            if (h2 == 0) {
                uint4 r;
                r.x = (unsigned)f2bf(a0) | ((unsigned)f2bf(a1) << 16);
                r.y = (unsigned)f2bf(a2) | ((unsigned)f2bf(a3) << 16);
                r.z = (unsigned)f2bf(a4) | ((unsigned)f2bf(a5) << 16);
                r.w = (unsigned)f2bf(a6) | ((unsigned)f2bf(a7) << 16);
                *(uint4*)&A[rl * 264 + h * 32 + (sub & 3) * 8] = r;
            }
        }
    }
    __syncthreads();
    const int lane = threadIdx.x & 63;
    const int w = threadIdx.x >> 6;
    const int lrow = lane & 15, lk = (lane >> 4) * 8;
    f32x4 acc[4][4];
#pragma unroll
    for (int i = 0; i < 4; ++i)
#pragma unroll
        for (int m = 0; m < 4; ++m) acc[i][m] = (f32x4){0.f, 0.f, 0.f, 0.f};
#define LOADB_O(dst, kk)                                                              \
    _Pragma("unroll") for (int i = 0; i < 4; ++i) dst[i] =                            \
        *(const bf16x8*)(WtO + (size_t)((w * 4 + i) * 16 + lrow) * 256 + (kk) * 32 + lk);
    {
        bf16x8 b0[4], b1[4];
        LOADB_O(b0, 0)
#pragma unroll
        for (int k2 = 0; k2 < 4; ++k2) {
            LOADB_O(b1, k2 * 2 + 1)
            MFMA_STEP4(b0, k2 * 2)
            if (k2 < 3) { LOADB_O(b0, k2 * 2 + 2) }
            MFMA_STEP4(b1, k2 * 2 + 1)
        }
    }
    const int g = lane >> 4;
    float4 bo[4], gm[4];
#pragma unroll
    for (int i = 0; i < 4; ++i) {
        bo[i] = *(const float4*)(b_out + (w * 4 + i) * 16 + g * 4);
        gm[i] = *(const float4*)(gamma + (w * 4 + i) * 16 + g * 4);
    }
#pragma unroll
    for (int m = 0; m < 4; ++m) {
        const size_t row = (size_t)(m0 + m * 16 + (lane & 15));
#pragma unroll
        for (int i = 0; i < 4; ++i) {
            const int col0 = (w * 4 + i) * 16 + g * 4;
            float4 q = *(const float4*)(query + row * 256 + col0);
            float4 o;
            o.x = q.x + gm[i].x * (acc[i][m][0] + bo[i].x);
            o.y = q.y + gm[i].y * (acc[i][m][1] + bo[i].y);
            o.z = q.z + gm[i].z * (acc[i][m][2] + bo[i].z);
            o.w = q.w + gm[i].w * (acc[i][m][3] + bo[i].w);
            *(float4*)(out + row * 256 + col0) = o;
        }
    }
}

extern "C" void kernel_launch(void* const* d_in, const int* in_sizes, int n_in,
                              void* d_out, int out_size, void* d_ws, size_t ws_size,
                              hipStream_t stream) {
    const float* query    = (const float*)d_in[0];
    const float* feat     = (const float*)d_in[1];
    const float* refpt    = (const float*)d_in[2];
    const float* qn_scale = (const float*)d_in[5];
    const float* qn_bias  = (const float*)d_in[6];
    const float* fn_scale = (const float*)d_in[7];
    const float* fn_bias  = (const float*)d_in[8];
    const float* W_value  = (const float*)d_in[9];
    const float* b_value  = (const float*)d_in[10];
    const float* W_off    = (const float*)d_in[11];
    const float* b_off    = (const float*)d_in[12];
    const float* W_attn   = (const float*)d_in[13];
    const float* b_attn   = (const float*)d_in[14];
    const float* W_out    = (const float*)d_in[15];
    const float* b_out    = (const float*)d_in[16];
    const float* gamma    = (const float*)d_in[17];
    float* out = (float*)d_out;

    char* ws = (char*)d_ws;
    unsigned short* WtV   = (unsigned short*)(ws);            // 128 KB
    unsigned short* WtO   = (unsigned short*)(ws + 131072);   // 128 KB
    unsigned short* WtC   = (unsigned short*)(ws + 262144);   // 48 KB -> 311296
    float* csumV = (float*)(ws + 311296);
    float* preV  = (float*)(ws + 312320);
    float* csumC = (float*)(ws + 313344);
    float* preC  = (float*)(ws + 313856);
    unsigned short* value = (unsigned short*)(ws + 315392);   // 32 MB (8 head planes)
    float4* samples       = (float4*)(ws + 315392 + 33554432); // 32 MB (4 planes)

    hipLaunchKernelGGL(k_prep, dim3(613), dim3(256), 0, stream,
                       W_value, W_off, W_attn, W_out,
                       fn_scale, fn_bias, qn_scale, qn_bias,
                       b_value, b_off, b_attn,
                       WtV, WtC, WtO, csumV, preV, csumC, preC);
    hipLaunchKernelGGL(k_mlp, dim3(2048), dim3(256), 0, stream,
                       feat, csumV, preV, WtV, value,
                       query, refpt, csumC, preC, WtC, samples);
    hipLaunchKernelGGL(k_gatherout, dim3(1024), dim3(256), 0, stream,
                       value, samples, WtO, b_out, gamma, query, out);
}